// Round 2
// baseline (725.535 us; speedup 1.0000x reference)
//
#include <hip/hip_runtime.h>

// ---------- types & helpers ----------
typedef __bf16 bf16x8 __attribute__((ext_vector_type(8)));
typedef float f32x4 __attribute__((ext_vector_type(4)));

__device__ __forceinline__ float bf2f(unsigned short u) {
  union { unsigned int i; float f; } c; c.i = ((unsigned int)u) << 16; return c.f;
}
__device__ __forceinline__ unsigned short f2bf(float f) {
  union { float f; unsigned int i; } c; c.f = f;
  unsigned int u = c.i;
  u += 0x7FFFu + ((u >> 16) & 1u);   // RNE
  return (unsigned short)(u >> 16);
}

#define GLDS16(g, l)                                                          \
  __builtin_amdgcn_global_load_lds(                                           \
      (const __attribute__((address_space(1))) void*)(g),                     \
      (__attribute__((address_space(3))) void*)(l), 16, 0, 0)

#define MFMA16(a, b, c) __builtin_amdgcn_mfma_f32_16x16x32_bf16(a, b, c, 0, 0, 0)

// ---------- constants ----------
// B=8192, D=1024, H=4, hd=256, C=4
// Self path folded:  self_out = X @ (Wo_s·Wv_s)^T + (bv_s@Wo_s^T + bo_s)
// ws layout (bytes):
//  Xcat   bf16 [32768 x 1024]   @ 0          (64 MB)
//  Wcat   bf16 [3072 x 1024]    @ 67108864   (6 MB)   rows: [Wk_c | Wv_c | Wq]
//  WoM2   bf16 [1024 x 2048]    @ 73400320   (4 MB)   row n = [Wo_c[n,:], M2[n,:]]
//  Wos_bf bf16 [1024 x 1024]    @ 77594624   (2 MB)
//  WvsT   bf16 [1024 x 1024]    @ 79691776   (2 MB)   WvsT[k][j] = Wv_s[j][k]
//  bias2  f32  [1024]           @ 81788928
//  Yproj  bf16 [32768 x 3072]   @ 81793024   (192 MB) cols: [KcX | VcX | QX->A]

// ---------- convert X1..X4 -> bf16 Xcat ----------
__global__ __launch_bounds__(256) void convert_x(
    const float* __restrict__ X1, const float* __restrict__ X2,
    const float* __restrict__ X3, const float* __restrict__ X4,
    unsigned short* __restrict__ Xcat)
{
  int gid = blockIdx.x * 256 + threadIdx.x;          // 8388608 threads
  size_t base = (size_t)gid * 4;
  int sec = (int)(base >> 23);
  int off = (int)(base & 8388607);
  const float* s = sec == 0 ? X1 : sec == 1 ? X2 : sec == 2 ? X3 : X4;
  float4 v = *(const float4*)(s + off);
  ushort4 o;
  o.x = f2bf(v.x); o.y = f2bf(v.y); o.z = f2bf(v.z); o.w = f2bf(v.w);
  *(ushort4*)(Xcat + base) = o;
}

// ---------- prep weights ----------
__global__ __launch_bounds__(256) void prep_w(
    const float* __restrict__ Wq,  const float* __restrict__ Wk_c,
    const float* __restrict__ Wv_c, const float* __restrict__ Wo_c,
    const float* __restrict__ Wo_s,
    unsigned short* __restrict__ Wcat, unsigned short* __restrict__ WoM2,
    unsigned short* __restrict__ Wos_bf)
{
  int gid = blockIdx.x * 256 + threadIdx.x;
  if (gid < 786432) {                                // Wcat: 3 x 1M elements
    int base = gid * 4;
    int sec = base >> 20, off = base & 1048575;
    const float* s = sec == 0 ? Wk_c : sec == 1 ? Wv_c : Wq;
    float4 v = *(const float4*)(s + off);
    ushort4 o;
    o.x = f2bf(v.x); o.y = f2bf(v.y); o.z = f2bf(v.z); o.w = f2bf(v.w);
    *(ushort4*)(Wcat + base) = o;
  } else if (gid < 1048576) {                        // Wo_c -> WoM2 cols 0..1023
    int idx = (gid - 786432) * 4;
    int n = idx >> 10, c = idx & 1023;
    float4 v = *(const float4*)(Wo_c + (size_t)n * 1024 + c);
    ushort4 o;
    o.x = f2bf(v.x); o.y = f2bf(v.y); o.z = f2bf(v.z); o.w = f2bf(v.w);
    *(ushort4*)(WoM2 + (size_t)n * 2048 + c) = o;
  } else if (gid < 1310720) {                        // Wo_s -> bf16 (linear)
    int base = (gid - 1048576) * 4;
    float4 v = *(const float4*)(Wo_s + base);
    ushort4 o;
    o.x = f2bf(v.x); o.y = f2bf(v.y); o.z = f2bf(v.z); o.w = f2bf(v.w);
    *(ushort4*)(Wos_bf + base) = o;
  }
}

// ---------- transpose Wv_s -> WvsT (bf16) ----------
__global__ __launch_bounds__(256) void transpose_wvs(
    const float* __restrict__ Wv_s, unsigned short* __restrict__ WvsT)
{
  __shared__ float tile[32][33];
  const int r = threadIdx.x >> 3;          // 0..31
  const int c4 = (threadIdx.x & 7) * 4;    // 0,4,..,28
  const int j0 = blockIdx.y * 32, k0 = blockIdx.x * 32;
  float4 v = *(const float4*)(Wv_s + (size_t)(j0 + r) * 1024 + k0 + c4);
  tile[r][c4] = v.x; tile[r][c4 + 1] = v.y; tile[r][c4 + 2] = v.z; tile[r][c4 + 3] = v.w;
  __syncthreads();
  ushort4 o;
  o.x = f2bf(tile[c4 + 0][r]); o.y = f2bf(tile[c4 + 1][r]);
  o.z = f2bf(tile[c4 + 2][r]); o.w = f2bf(tile[c4 + 3][r]);
  *(ushort4*)(WvsT + (size_t)(k0 + r) * 1024 + j0 + c4) = o;
}

// ---------- bias2 = bo_c + bo_s + Wo_s @ bv_s ----------
__global__ __launch_bounds__(256) void bias2_kernel(
    const float* __restrict__ Wo_s, const float* __restrict__ bv_s,
    const float* __restrict__ bo_c, const float* __restrict__ bo_s,
    float* __restrict__ bias2)
{
  const int wv = threadIdx.x >> 6, l = threadIdx.x & 63;
  const int n = blockIdx.x * 4 + wv;
  const float* row = Wo_s + (size_t)n * 1024;
  float s = 0.f;
#pragma unroll
  for (int it = 0; it < 4; ++it) {
    int j = it * 256 + l * 4;
    float4 w = *(const float4*)(row + j);
    float4 b = *(const float4*)(bv_s + j);
    s += w.x * b.x + w.y * b.y + w.z * b.z + w.w * b.w;
  }
#pragma unroll
  for (int d = 1; d < 64; d <<= 1) s += __shfl_xor(s, d);
  if (l == 0) bias2[n] = s + bo_c[n] + bo_s[n];
}

// ---------- small GEMM (kept for M2): C[M,N] = A[M,K] * Bw[N,K]^T ----------
// 128x128 block tile, BK=32, 256 threads = 4 waves (2x2), 4x4 MFMA 16x16x32 each.
template<bool OUT_F32, bool HAS_BIAS>
__global__ __launch_bounds__(256) void gemm_bt(
    const unsigned short* __restrict__ A1, int lda1, int K1,
    const unsigned short* __restrict__ A2, int lda2, int K2,
    const unsigned short* __restrict__ Bw, int ldb,
    void* __restrict__ Cout, int ldc,
    const float* __restrict__ bias)
{
  __shared__ char lds[16384];
  char* ldsA = lds;
  char* ldsB = lds + 8192;

  const int t = threadIdx.x;
  const int l = t & 63;
  const int wv = t >> 6;
  const int wr = wv >> 1, wc = wv & 1;
  const int bM = blockIdx.y * 128, bN = blockIdx.x * 128;

  const int pa0 = t, pa1 = t + 256;
  const int ra0 = pa0 >> 2, ra1 = pa1 >> 2;
  const int ca0 = (((pa0 & 3) ^ ((ra0 >> 1) & 3))) * 8;
  const int ca1 = (((pa1 & 3) ^ ((ra1 >> 1) & 3))) * 8;
  const unsigned short* gB0 = Bw + (size_t)(bN + ra0) * ldb + ca0;
  const unsigned short* gB1 = Bw + (size_t)(bN + ra1) * ldb + ca1;
  char* lA0 = ldsA + pa0 * 16; char* lA1 = ldsA + pa1 * 16;
  char* lB0 = ldsB + pa0 * 16; char* lB1 = ldsB + pa1 * 16;

  const int rA = wr * 64 + (l & 15);
  const int rB = wc * 64 + (l & 15);
  const int cA = ((l >> 4) ^ ((rA >> 1) & 3)) * 16;
  const int cB = ((l >> 4) ^ ((rB >> 1) & 3)) * 16;
  const char* fA = ldsA + rA * 64 + cA;
  const char* fB = ldsB + rB * 64 + cB;

  f32x4 acc[4][4] = {};

  const unsigned short* gA0 = A1 + (size_t)(bM + ra0) * lda1 + ca0;
  const unsigned short* gA1 = A1 + (size_t)(bM + ra1) * lda1 + ca1;

  for (int src = 0; src < 2; ++src) {
    const int Kc = src ? K2 : K1;
    if (src) {
      if (K2 == 0) break;
      gA0 = A2 + (size_t)(bM + ra0) * lda2 + ca0;
      gA1 = A2 + (size_t)(bM + ra1) * lda2 + ca1;
    }
    for (int k0 = 0; k0 < Kc; k0 += 32) {
      GLDS16(gA0, lA0); GLDS16(gA1, lA1);
      GLDS16(gB0, lB0); GLDS16(gB1, lB1);
      gA0 += 32; gA1 += 32; gB0 += 32; gB1 += 32;
      __syncthreads();

      bf16x8 af[4], bfv[4];
#pragma unroll
      for (int i = 0; i < 4; ++i) af[i] = *(const bf16x8*)(fA + i * 1024);
#pragma unroll
      for (int i = 0; i < 4; ++i) bfv[i] = *(const bf16x8*)(fB + i * 1024);
#pragma unroll
      for (int mt = 0; mt < 4; ++mt)
#pragma unroll
        for (int nt = 0; nt < 4; ++nt)
          acc[mt][nt] = MFMA16(af[mt], bfv[nt], acc[mt][nt]);
      __syncthreads();
    }
  }

  const int mrow = bM + wr * 64 + ((l >> 4) << 2);
  const int ncol = bN + wc * 64 + (l & 15);
  float bvals[4];
  if (HAS_BIAS) {
#pragma unroll
    for (int nt = 0; nt < 4; ++nt) bvals[nt] = bias[ncol + nt * 16];
  }
#pragma unroll
  for (int mt = 0; mt < 4; ++mt)
#pragma unroll
    for (int nt = 0; nt < 4; ++nt)
#pragma unroll
      for (int r = 0; r < 4; ++r) {
        size_t idx = (size_t)(mrow + mt * 16 + r) * ldc + (ncol + nt * 16);
        float v = acc[mt][nt][r];
        if (HAS_BIAS) v += bvals[nt];
        if (OUT_F32) ((float*)Cout)[idx] = v;
        else         ((unsigned short*)Cout)[idx] = f2bf(v);
      }
}

// ---------- big GEMM: 256x256 tile, BK=64, 8-phase counted-vmcnt schedule ----------
// C[M,N] = [A1|A2][M,K1+K2] * Bw[N,K]^T (+bias).
// 512 thr = 8 waves (2M x 4N); per-wave 128x64 out = acc[8][4] f32x4.
// LDS 128 KiB: buf{0,1} x [A.kh0|A.kh1|B.kh0|B.kh1] x 16 KiB (kh = 32-k half of BK=64).
// Per K-tile t (buf p=t&1), 4 phases:
//  ph1: ds_read kh0 (8A+4B) | stage B.kh1(t+1)->buf p^1 | bar | lgkm0 | 16 MFMA n0-1
//  ph2: stage A.kh0(t+2)->buf p | vmcnt(6/4/0) | bar | 16 MFMA n2-3
//  ph3: ds_read kh1 | stage B.kh0(t+2) | bar | lgkm0 | 16 MFMA n0-1
//  ph4: stage A.kh1(t+2) | bar | 16 MFMA n2-3
// vmcnt ledger: needed at t.ph2 = {A1(t),B1(t),A0(t+1),B0(t+1)}; issued-after = 3 halves
// = 6 loads -> vmcnt(6); t==NT-2 -> 4; t==NT-1 -> 0. Prologue: 7 halves, vmcnt(10).
// Every restaged LDS region was fully read >=1 barrier earlier (reads drain at each
// phase's lgkmcnt(0) before that phase's closing barrier).
// Swizzle: 16B k-chunk XOR (chunk ^ (row>>1)&3), pre-swizzled global source (linear
// global_load_lds dest) + swizzled ds_read -> 2-way LDS conflict (free).
template<bool OUT_F32, bool HAS_BIAS>
__global__ __launch_bounds__(512, 2) void gemm256(
    const unsigned short* __restrict__ A1, int lda1, int K1,
    const unsigned short* __restrict__ A2, int lda2, int K2,
    const unsigned short* __restrict__ Bw, int ldb,
    void* __restrict__ Cout, int ldc,
    const float* __restrict__ bias)
{
  __shared__ __align__(128) char lds[131072];

  const int tid = threadIdx.x;
  const int l  = tid & 63;
  const int wv = tid >> 6;
  const int wr = wv >> 2, wc = wv & 3;     // 2 x 4 wave grid

  // XCD-aware bijective swizzle (nwg % 8 == 0 for our grids)
  const int nN = gridDim.x;
  int lin = blockIdx.y * nN + blockIdx.x;
  int nwg = nN * gridDim.y;
  int id2 = ((nwg & 7) == 0) ? ((lin & 7) * (nwg >> 3) + (lin >> 3)) : lin;
  const int bM = (id2 / nN) * 256;
  const int bN = (id2 % nN) * 256;

  const int NT1 = K1 >> 6;
  const int NT  = (K1 + K2) >> 6;

  // ---- staging invariants: thread stages 16B chunks p=tid (row tid>>2) and
  // p=tid+512 (row tid>>2 + 128); phys chunk tid&3; global col pre-swizzled.
  const int sr0  = tid >> 2;
  const int colE = ((tid & 3) ^ ((sr0 >> 1) & 3)) * 8;
  const unsigned short* pA1g0 = A1 + (size_t)(bM + sr0) * lda1 + colE;
  const unsigned short* pA1g1 = A1 + (size_t)(bM + sr0 + 128) * lda1 + colE;
  const unsigned short* pA2g0 = (K2 > 0) ? A2 + (size_t)(bM + sr0) * lda2 + colE : pA1g0;
  const unsigned short* pA2g1 = (K2 > 0) ? A2 + (size_t)(bM + sr0 + 128) * lda2 + colE : pA1g1;
  const unsigned short* pBg0  = Bw + (size_t)(bN + sr0) * ldb + colE;
  const unsigned short* pBg1  = Bw + (size_t)(bN + sr0 + 128) * ldb + colE;
  char* ldsw = lds + tid * 16;

  auto stageA = [&](int tt, int kh) {
    const unsigned short *p0, *p1; int tc;
    if (tt < NT1) { p0 = pA1g0; p1 = pA1g1; tc = (tt << 6) + (kh << 5); }
    else          { p0 = pA2g0; p1 = pA2g1; tc = ((tt - NT1) << 6) + (kh << 5); }
    unsigned off = (unsigned)((tt & 1) << 16) + (unsigned)(kh << 14);
    GLDS16(p0 + tc, ldsw + off);
    GLDS16(p1 + tc, ldsw + off + 8192);
  };
  auto stageB = [&](int tt, int kh) {
    int tc = (tt << 6) + (kh << 5);
    unsigned off = (unsigned)((tt & 1) << 16) + 32768u + (unsigned)(kh << 14);
    GLDS16(pBg0 + tc, ldsw + off);
    GLDS16(pBg1 + tc, ldsw + off + 8192);
  };

  // ---- fragment-read bases (swizzle invariant across 16-row strides)
  const int swz = ((l >> 4) ^ (((l & 15) >> 1) & 3)) << 4;
  const char* rdA0 = lds + ((wr * 128 + (l & 15)) * 64 + swz);
  const char* rdB0 = lds + (32768 + (wc * 64 + (l & 15)) * 64 + swz);

  f32x4 acc[8][4] = {};

  // ---- prologue: stage A0(0),B0(0),A1(0),B1(0),A0(1),B0(1),A1(1)
  stageA(0, 0); stageB(0, 0); stageA(0, 1); stageB(0, 1);
  stageA(1, 0); stageB(1, 0); stageA(1, 1);
  asm volatile("s_waitcnt vmcnt(10)" ::: "memory");
  __builtin_amdgcn_s_barrier();

  for (int t = 0; t < NT; ++t) {
    const char* rA = rdA0 + ((t & 1) << 16);
    const char* rB = rdB0 + ((t & 1) << 16);
    bf16x8 af[8], bfr[4];

    // -------- phase 1: kh0 reads, MFMA n0-1 --------
#pragma unroll
    for (int m = 0; m < 8; ++m) af[m] = *(const bf16x8*)(rA + m * 1024);
#pragma unroll
    for (int n = 0; n < 4; ++n) bfr[n] = *(const bf16x8*)(rB + n * 1024);
    if (t + 1 < NT) stageB(t + 1, 1);
    __builtin_amdgcn_s_barrier();
    asm volatile("s_waitcnt lgkmcnt(0)" ::: "memory");
    __builtin_amdgcn_s_setprio(1);
#pragma unroll
    for (int m = 0; m < 8; ++m) {
      acc[m][0] = MFMA16(af[m], bfr[0], acc[m][0]);
      acc[m][1] = MFMA16(af[m], bfr[1], acc[m][1]);
    }
    __builtin_amdgcn_s_setprio(0);
    __builtin_amdgcn_s_barrier();

    // -------- phase 2: MFMA n2-3 (kh0), vmcnt gate --------
    if (t + 2 < NT) stageA(t + 2, 0);
    if (t < NT - 2)       asm volatile("s_waitcnt vmcnt(6)" ::: "memory");
    else if (t == NT - 2) asm volatile("s_waitcnt vmcnt(4)" ::: "memory");
    else                  asm volatile("s_waitcnt vmcnt(0)" ::: "memory");
    __builtin_amdgcn_s_barrier();
    __builtin_amdgcn_s_setprio(1);
#pragma unroll
    for (int m = 0; m < 8; ++m) {
      acc[m][2] = MFMA16(af[m], bfr[2], acc[m][2]);
      acc[m][3] = MFMA16(af[m], bfr[3], acc[m][3]);
    }
    __builtin_amdgcn_s_setprio(0);
    __builtin_amdgcn_s_barrier();

    // -------- phase 3: kh1 reads, MFMA n0-1 --------
#pragma unroll
    for (int m = 0; m < 8; ++m) af[m] = *(const bf16x8*)(rA + 16384 + m * 1024);
#pragma unroll
    for (int n = 0; n < 4; ++n) bfr[n] = *(const bf16x8*)(rB + 16384 + n * 1024);
    if (t + 2 < NT) stageB(t + 2, 0);
    __builtin_amdgcn_s_barrier();
    asm volatile("s_waitcnt lgkmcnt(0)" ::: "memory");
    __builtin_amdgcn_s_setprio(1);
#pragma unroll
    for (int m = 0; m < 8; ++m) {
      acc[m][0] = MFMA16(af[m], bfr[0], acc[m][0]);
      acc[m][1] = MFMA16(af[m], bfr[1], acc[m][1]);
    }
    __builtin_amdgcn_s_setprio(0);
    __builtin_amdgcn_s_barrier();

    // -------- phase 4: MFMA n2-3 (kh1) --------
    if (t + 2 < NT) stageA(t + 2, 1);
    __builtin_amdgcn_s_barrier();
    __builtin_amdgcn_s_setprio(1);
#pragma unroll
    for (int m = 0; m < 8; ++m) {
      acc[m][2] = MFMA16(af[m], bfr[2], acc[m][2]);
      acc[m][3] = MFMA16(af[m], bfr[3], acc[m][3]);
    }
    __builtin_amdgcn_s_setprio(0);
    __builtin_amdgcn_s_barrier();
  }

  // ---- epilogue: D row=(l>>4)*4+r, col=l&15 (verified m89/m91 layout)
  const int mb = bM + wr * 128 + ((l >> 4) << 2);
  const int nb = bN + wc * 64 + (l & 15);
  float bvals[4];
  if (HAS_BIAS) {
#pragma unroll
    for (int n = 0; n < 4; ++n) bvals[n] = bias[nb + n * 16];
  }
#pragma unroll
  for (int m = 0; m < 8; ++m)
#pragma unroll
    for (int n = 0; n < 4; ++n)
#pragma unroll
      for (int r = 0; r < 4; ++r) {
        size_t idx = (size_t)(mb + m * 16 + r) * ldc + (nb + n * 16);
        float v = acc[m][n][r];
        if (HAS_BIAS) v += bvals[n];
        if (OUT_F32) ((float*)Cout)[idx] = v;
        else         ((unsigned short*)Cout)[idx] = f2bf(v);
      }
}

// ---------- attention (3 keys, 4 heads) ----------
__global__ __launch_bounds__(256) void attn_kernel(
    unsigned short* __restrict__ Yp,
    const float* __restrict__ bq,  const float* __restrict__ bkc,
    const float* __restrict__ bvc)
{
  const int b = blockIdx.x;
  const int h = threadIdx.x >> 6;
  const int l = threadIdx.x & 63;
  const int e0 = h * 256 + l * 4;

  const float4 bqv = *(const float4*)(bq + e0);
  const float4 bkv = *(const float4*)(bkc + e0);
  const float4 bvv = *(const float4*)(bvc + e0);

  float q[4][4], kc[4][4], vc[4][4];
  size_t rb[4];
#pragma unroll
  for (int i = 0; i < 4; ++i) {
    rb[i] = ((size_t)i * 8192 + b) * 3072;
    ushort4 qq = *(const ushort4*)(Yp + rb[i] + 2048 + e0);
    ushort4 kk = *(const ushort4*)(Yp + rb[i] + e0);
    ushort4 vv = *(const ushort4*)(Yp + rb[i] + 1024 + e0);
    q[i][0] = bf2f(qq.x) + bqv.x; q[i][1] = bf2f(qq.y) + bqv.y;
    q[i][2] = bf2f(qq.z) + bqv.z; q[i][3] = bf2f(qq.w) + bqv.w;
    kc[i][0] = bf2f(kk.x); kc[i][1] = bf2f(kk.y);
    kc[i][2] = bf2f(kk.z); kc[i][3] = bf2f(kk.w);
    vc[i][0] = bf2f(vv.x); vc[i][1] = bf2f(vv.y);
    vc[i][2] = bf2f(vv.z); vc[i][3] = bf2f(vv.w);
  }

  float u[4][4], tb[4];
#pragma unroll
  for (int i = 0; i < 4; ++i) {
    tb[i] = q[i][0]*bkv.x + q[i][1]*bkv.y + q[i][2]*bkv.z + q[i][3]*bkv.w;
#pragma unroll
    for (int j = 0; j < 4; ++j)
      u[i][j] = q[i][0]*kc[j][0] + q[i][1]*kc[j][1] + q[i][2]*kc[j][2] + q[i][3]*kc[j][3];
  }
#pragma unroll
  for (int d = 1; d < 64; d <<= 1) {
#pragma unroll
    for (int i = 0; i < 4; ++i) {
      tb[i] += __shfl_xor(tb[i], d);
#pragma unroll
      for (int j = 0; j < 4; ++j) u[i][j] += __shfl_xor(u[i][j], d);
    }
  }

#pragma unroll
  for (int i = 0; i < 4; ++i) {
    float s[4], a[4];
    float mx = -1e30f;
#pragma unroll
    for (int j = 0; j < 4; ++j) {
      s[j] = (u[i][i] - u[i][j] + tb[i]) * 0.0625f;
      if (j != i) mx = fmaxf(mx, s[j]);
    }
    float den = 0.f;
#pragma unroll
    for (int j = 0; j < 4; ++j) {
      a[j] = (j == i) ? 0.f : __expf(s[j] - mx);
      den += a[j];
    }
    float inv = 1.f / den;
#pragma unroll
    for (int j = 0; j < 4; ++j) a[j] *= inv;

    float o0 = vc[i][0] + bvv.x, o1 = vc[i][1] + bvv.y;
    float o2 = vc[i][2] + bvv.z, o3 = vc[i][3] + bvv.w;
#pragma unroll
    for (int j = 0; j < 4; ++j) {
      o0 -= a[j] * vc[j][0]; o1 -= a[j] * vc[j][1];
      o2 -= a[j] * vc[j][2]; o3 -= a[j] * vc[j][3];
    }
    ushort4 w;
    w.x = f2bf(o0); w.y = f2bf(o1); w.z = f2bf(o2); w.w = f2bf(o3);
    *(ushort4*)(Yp + rb[i] + 2048 + e0) = w;
  }
}

// ---------- logits ----------
__global__ __launch_bounds__(256) void logits_kernel(
    const float* __restrict__ feats, const float* __restrict__ Wc,
    const float* __restrict__ bc, float* __restrict__ out)
{
  __shared__ float w[4096];
  const int t = threadIdx.x;
  for (int i = t; i < 4096; i += 256) w[i] = Wc[i];
  __syncthreads();
  const int wave = t >> 6, l = t & 63;
  const int row = blockIdx.x * 4 + wave;
  const float* f = feats + (size_t)row * 1024;
  float s0 = 0.f, s1 = 0.f, s2 = 0.f, s3 = 0.f;
#pragma unroll
  for (int c4 = 0; c4 < 4; ++c4) {
    int e = c4 * 256 + l * 4;
    float4 x  = *(const float4*)(f + e);
    float4 w0 = *(const float4*)(w + e);
    float4 w1 = *(const float4*)(w + 1024 + e);
    float4 w2 = *(const float4*)(w + 2048 + e);
    float4 w3 = *(const float4*)(w + 3072 + e);
    s0 += x.x*w0.x + x.y*w0.y + x.z*w0.z + x.w*w0.w;
    s1 += x.x*w1.x + x.y*w1.y + x.z*w1.z + x.w*w1.w;
    s2 += x.x*w2.x + x.y*w2.y + x.z*w2.z + x.w*w2.w;
    s3 += x.x*w3.x + x.y*w3.y + x.z*w3.z + x.w*w3.w;
  }
#pragma unroll
  for (int d = 1; d < 64; d <<= 1) {
    s0 += __shfl_xor(s0, d); s1 += __shfl_xor(s1, d);
    s2 += __shfl_xor(s2, d); s3 += __shfl_xor(s3, d);
  }
  if (l < 4) {
    float s = (l == 0) ? s0 : (l == 1) ? s1 : (l == 2) ? s2 : s3;
    out[(size_t)row * 4 + l] = s + bc[l];
  }
}

// ---------- launch ----------
extern "C" void kernel_launch(void* const* d_in, const int* in_sizes, int n_in,
                              void* d_out, int out_size, void* d_ws, size_t ws_size,
                              hipStream_t stream) {
  const float* X1   = (const float*)d_in[0];
  const float* X2   = (const float*)d_in[1];
  const float* X3   = (const float*)d_in[2];
  const float* X4   = (const float*)d_in[3];
  const float* Wq   = (const float*)d_in[4];
  const float* bq   = (const float*)d_in[5];
  // d_in[6] Wk_s, d_in[7] bk_s: unused (softmax over a single key == identity)
  const float* Wv_s = (const float*)d_in[8];
  const float* bv_s = (const float*)d_in[9];
  const float* Wo_s = (const float*)d_in[10];
  const float* bo_s = (const float*)d_in[11];
  const float* Wk_c = (const float*)d_in[12];
  const float* bk_c = (const float*)d_in[13];
  const float* Wv_c = (const float*)d_in[14];
  const float* bv_c = (const float*)d_in[15];
  const float* Wo_c = (const float*)d_in[16];
  const float* bo_c = (const float*)d_in[17];
  const float* Wc   = (const float*)d_in[18];
  const float* bc   = (const float*)d_in[19];

  char* ws = (char*)d_ws;
  unsigned short* Xcat   = (unsigned short*)(ws + 0);
  unsigned short* Wcat   = (unsigned short*)(ws + 67108864);
  unsigned short* WoM2   = (unsigned short*)(ws + 73400320);
  unsigned short* Wos_bf = (unsigned short*)(ws + 77594624);
  unsigned short* WvsT   = (unsigned short*)(ws + 79691776);
  float*          bias2  = (float*)        (ws + 81788928);
  unsigned short* Yproj  = (unsigned short*)(ws + 81793024);
  float* out = (float*)d_out;

  convert_x<<<32768, 256, 0, stream>>>(X1, X2, X3, X4, Xcat);
  prep_w<<<5120, 256, 0, stream>>>(Wq, Wk_c, Wv_c, Wo_c, Wo_s, Wcat, WoM2, Wos_bf);
  transpose_wvs<<<dim3(32, 32), 256, 0, stream>>>(Wv_s, WvsT);
  bias2_kernel<<<256, 256, 0, stream>>>(Wo_s, bv_s, bo_c, bo_s, bias2);
  // M2 = Wo_s @ Wv_s  -> WoM2 cols 1024..2047 (small, keep proven 128^2 kernel)
  gemm_bt<false, false><<<dim3(8, 8), 256, 0, stream>>>(
      Wos_bf, 1024, 1024, nullptr, 0, 0, WvsT, 1024,
      (void*)(WoM2 + 1024), 2048, nullptr);
  // Yproj[i*B+b, :] = [KcX | VcX | QX]   (256^2 8-phase)
  gemm256<false, false><<<dim3(12, 128), 512, 0, stream>>>(
      Xcat, 1024, 1024, nullptr, 0, 0, Wcat, 1024,
      (void*)Yproj, 3072, nullptr);
  attn_kernel<<<8192, 256, 0, stream>>>(Yproj, bq, bk_c, bv_c);
  // d = [A | X] @ [Wo_c | M2]^T + bias2   (256^2 8-phase, dual-A concat)
  gemm256<true, true><<<dim3(4, 128), 512, 0, stream>>>(
      Yproj + 2048, 3072, 1024, Xcat, 1024, 1024, WoM2, 2048,
      (void*)out, 1024, bias2);
  logits_kernel<<<8192, 256, 0, stream>>>(out, Wc, bc, out + 33554432);
}

// Round 3
// 710.654 us; speedup vs baseline: 1.0209x; 1.0209x over previous
//
#include <hip/hip_runtime.h>

// ---------- types & helpers ----------
typedef __bf16 bf16x8 __attribute__((ext_vector_type(8)));
typedef float f32x4 __attribute__((ext_vector_type(4)));

__device__ __forceinline__ float bf2f(unsigned short u) {
  union { unsigned int i; float f; } c; c.i = ((unsigned int)u) << 16; return c.f;
}
__device__ __forceinline__ unsigned short f2bf(float f) {
  union { float f; unsigned int i; } c; c.f = f;
  unsigned int u = c.i;
  u += 0x7FFFu + ((u >> 16) & 1u);   // RNE
  return (unsigned short)(u >> 16);
}

#define GLDS16(g, l)                                                          \
  __builtin_amdgcn_global_load_lds(                                           \
      (const __attribute__((address_space(1))) void*)(g),                     \
      (__attribute__((address_space(3))) void*)(l), 16, 0, 0)

#define MFMA16(a, b, c) __builtin_amdgcn_mfma_f32_16x16x32_bf16(a, b, c, 0, 0, 0)

// ---------- constants ----------
// B=8192, D=1024, H=4, hd=256, C=4
// Self path folded:  self_out = X @ (Wo_s·Wv_s)^T + (bv_s@Wo_s^T + bo_s)
// ws layout (bytes):
//  Xcat   bf16 [32768 x 1024]   @ 0          (64 MB)
//  Wcat   bf16 [3072 x 1024]    @ 67108864   (6 MB)   rows: [Wk_c | Wv_c | Wq]
//  WoM2   bf16 [1024 x 2048]    @ 73400320   (4 MB)   row n = [Wo_c[n,:], M2[n,:]]
//  Wos_bf bf16 [1024 x 1024]    @ 77594624   (2 MB)
//  WvsT   bf16 [1024 x 1024]    @ 79691776   (2 MB)   WvsT[k][j] = Wv_s[j][k]
//  bias2  f32  [1024]           @ 81788928
//  Yproj  bf16 [32768 x 3072]   @ 81793024   (192 MB) cols: [KcX | VcX | QX->A]

// ---------- convert X1..X4 -> bf16 Xcat ----------
__global__ __launch_bounds__(256) void convert_x(
    const float* __restrict__ X1, const float* __restrict__ X2,
    const float* __restrict__ X3, const float* __restrict__ X4,
    unsigned short* __restrict__ Xcat)
{
  int gid = blockIdx.x * 256 + threadIdx.x;          // 8388608 threads
  size_t base = (size_t)gid * 4;
  int sec = (int)(base >> 23);
  int off = (int)(base & 8388607);
  const float* s = sec == 0 ? X1 : sec == 1 ? X2 : sec == 2 ? X3 : X4;
  float4 v = *(const float4*)(s + off);
  ushort4 o;
  o.x = f2bf(v.x); o.y = f2bf(v.y); o.z = f2bf(v.z); o.w = f2bf(v.w);
  *(ushort4*)(Xcat + base) = o;
}

// ---------- prep weights ----------
__global__ __launch_bounds__(256) void prep_w(
    const float* __restrict__ Wq,  const float* __restrict__ Wk_c,
    const float* __restrict__ Wv_c, const float* __restrict__ Wo_c,
    const float* __restrict__ Wo_s,
    unsigned short* __restrict__ Wcat, unsigned short* __restrict__ WoM2,
    unsigned short* __restrict__ Wos_bf)
{
  int gid = blockIdx.x * 256 + threadIdx.x;
  if (gid < 786432) {                                // Wcat: 3 x 1M elements
    int base = gid * 4;
    int sec = base >> 20, off = base & 1048575;
    const float* s = sec == 0 ? Wk_c : sec == 1 ? Wv_c : Wq;
    float4 v = *(const float4*)(s + off);
    ushort4 o;
    o.x = f2bf(v.x); o.y = f2bf(v.y); o.z = f2bf(v.z); o.w = f2bf(v.w);
    *(ushort4*)(Wcat + base) = o;
  } else if (gid < 1048576) {                        // Wo_c -> WoM2 cols 0..1023
    int idx = (gid - 786432) * 4;
    int n = idx >> 10, c = idx & 1023;
    float4 v = *(const float4*)(Wo_c + (size_t)n * 1024 + c);
    ushort4 o;
    o.x = f2bf(v.x); o.y = f2bf(v.y); o.z = f2bf(v.z); o.w = f2bf(v.w);
    *(ushort4*)(WoM2 + (size_t)n * 2048 + c) = o;
  } else if (gid < 1310720) {                        // Wo_s -> bf16 (linear)
    int base = (gid - 1048576) * 4;
    float4 v = *(const float4*)(Wo_s + base);
    ushort4 o;
    o.x = f2bf(v.x); o.y = f2bf(v.y); o.z = f2bf(v.z); o.w = f2bf(v.w);
    *(ushort4*)(Wos_bf + base) = o;
  }
}

// ---------- transpose Wv_s -> WvsT (bf16) ----------
__global__ __launch_bounds__(256) void transpose_wvs(
    const float* __restrict__ Wv_s, unsigned short* __restrict__ WvsT)
{
  __shared__ float tile[32][33];
  const int r = threadIdx.x >> 3;          // 0..31
  const int c4 = (threadIdx.x & 7) * 4;    // 0,4,..,28
  const int j0 = blockIdx.y * 32, k0 = blockIdx.x * 32;
  float4 v = *(const float4*)(Wv_s + (size_t)(j0 + r) * 1024 + k0 + c4);
  tile[r][c4] = v.x; tile[r][c4 + 1] = v.y; tile[r][c4 + 2] = v.z; tile[r][c4 + 3] = v.w;
  __syncthreads();
  ushort4 o;
  o.x = f2bf(tile[c4 + 0][r]); o.y = f2bf(tile[c4 + 1][r]);
  o.z = f2bf(tile[c4 + 2][r]); o.w = f2bf(tile[c4 + 3][r]);
  *(ushort4*)(WvsT + (size_t)(k0 + r) * 1024 + j0 + c4) = o;
}

// ---------- bias2 = bo_c + bo_s + Wo_s @ bv_s ----------
__global__ __launch_bounds__(256) void bias2_kernel(
    const float* __restrict__ Wo_s, const float* __restrict__ bv_s,
    const float* __restrict__ bo_c, const float* __restrict__ bo_s,
    float* __restrict__ bias2)
{
  const int wv = threadIdx.x >> 6, l = threadIdx.x & 63;
  const int n = blockIdx.x * 4 + wv;
  const float* row = Wo_s + (size_t)n * 1024;
  float s = 0.f;
#pragma unroll
  for (int it = 0; it < 4; ++it) {
    int j = it * 256 + l * 4;
    float4 w = *(const float4*)(row + j);
    float4 b = *(const float4*)(bv_s + j);
    s += w.x * b.x + w.y * b.y + w.z * b.z + w.w * b.w;
  }
#pragma unroll
  for (int d = 1; d < 64; d <<= 1) s += __shfl_xor(s, d);
  if (l == 0) bias2[n] = s + bo_c[n] + bo_s[n];
}

// ---------- small GEMM (kept for M2): C[M,N] = A[M,K] * Bw[N,K]^T ----------
template<bool OUT_F32, bool HAS_BIAS>
__global__ __launch_bounds__(256) void gemm_bt(
    const unsigned short* __restrict__ A1, int lda1, int K1,
    const unsigned short* __restrict__ A2, int lda2, int K2,
    const unsigned short* __restrict__ Bw, int ldb,
    void* __restrict__ Cout, int ldc,
    const float* __restrict__ bias)
{
  __shared__ char lds[16384];
  char* ldsA = lds;
  char* ldsB = lds + 8192;

  const int t = threadIdx.x;
  const int l = t & 63;
  const int wv = t >> 6;
  const int wr = wv >> 1, wc = wv & 1;
  const int bM = blockIdx.y * 128, bN = blockIdx.x * 128;

  const int pa0 = t, pa1 = t + 256;
  const int ra0 = pa0 >> 2, ra1 = pa1 >> 2;
  const int ca0 = (((pa0 & 3) ^ ((ra0 >> 1) & 3))) * 8;
  const int ca1 = (((pa1 & 3) ^ ((ra1 >> 1) & 3))) * 8;
  const unsigned short* gB0 = Bw + (size_t)(bN + ra0) * ldb + ca0;
  const unsigned short* gB1 = Bw + (size_t)(bN + ra1) * ldb + ca1;
  char* lA0 = ldsA + pa0 * 16; char* lA1 = ldsA + pa1 * 16;
  char* lB0 = ldsB + pa0 * 16; char* lB1 = ldsB + pa1 * 16;

  const int rA = wr * 64 + (l & 15);
  const int rB = wc * 64 + (l & 15);
  const int cA = ((l >> 4) ^ ((rA >> 1) & 3)) * 16;
  const int cB = ((l >> 4) ^ ((rB >> 1) & 3)) * 16;
  const char* fA = ldsA + rA * 64 + cA;
  const char* fB = ldsB + rB * 64 + cB;

  f32x4 acc[4][4] = {};

  const unsigned short* gA0 = A1 + (size_t)(bM + ra0) * lda1 + ca0;
  const unsigned short* gA1 = A1 + (size_t)(bM + ra1) * lda1 + ca1;

  for (int src = 0; src < 2; ++src) {
    const int Kc = src ? K2 : K1;
    if (src) {
      if (K2 == 0) break;
      gA0 = A2 + (size_t)(bM + ra0) * lda2 + ca0;
      gA1 = A2 + (size_t)(bM + ra1) * lda2 + ca1;
    }
    for (int k0 = 0; k0 < Kc; k0 += 32) {
      GLDS16(gA0, lA0); GLDS16(gA1, lA1);
      GLDS16(gB0, lB0); GLDS16(gB1, lB1);
      gA0 += 32; gA1 += 32; gB0 += 32; gB1 += 32;
      __syncthreads();

      bf16x8 af[4], bfv[4];
#pragma unroll
      for (int i = 0; i < 4; ++i) af[i] = *(const bf16x8*)(fA + i * 1024);
#pragma unroll
      for (int i = 0; i < 4; ++i) bfv[i] = *(const bf16x8*)(fB + i * 1024);
#pragma unroll
      for (int mt = 0; mt < 4; ++mt)
#pragma unroll
        for (int nt = 0; nt < 4; ++nt)
          acc[mt][nt] = MFMA16(af[mt], bfv[nt], acc[mt][nt]);
      __syncthreads();
    }
  }

  const int mrow = bM + wr * 64 + ((l >> 4) << 2);
  const int ncol = bN + wc * 64 + (l & 15);
  float bvals[4];
  if (HAS_BIAS) {
#pragma unroll
    for (int nt = 0; nt < 4; ++nt) bvals[nt] = bias[ncol + nt * 16];
  }
#pragma unroll
  for (int mt = 0; mt < 4; ++mt)
#pragma unroll
    for (int nt = 0; nt < 4; ++nt)
#pragma unroll
      for (int r = 0; r < 4; ++r) {
        size_t idx = (size_t)(mrow + mt * 16 + r) * ldc + (ncol + nt * 16);
        float v = acc[mt][nt][r];
        if (HAS_BIAS) v += bvals[nt];
        if (OUT_F32) ((float*)Cout)[idx] = v;
        else         ((unsigned short*)Cout)[idx] = f2bf(v);
      }
}

// ---------- big GEMM: 256x256 tile, BK=64, 4-phase 1-barrier/phase schedule ----------
// C[M,N] = [A1|A2][M,K1+K2] * Bw[N,K]^T (+bias).
// 512 thr = 8 waves (2M x 4N); per-wave 128x64 out = acc[8][4] f32x4.
// LDS 128 KiB: buf{0,1} x [A.kh0|A.kh1|B.kh0|B.kh1] x 16 KiB (kh = 32-k half of BK=64).
// Per K-tile t (buf p=t&1), 4 phases, ONE barrier each, no lgkmcnt asm (compiler
// staircases ds_read->MFMA within the phase):
//  ph1: read kh0 (12x b128) | stage B(t+1,1) | MFMA kh0 n01 | bar
//  ph2: stage A(t+2,0) | MFMA kh0 n23 | vmcnt(10/8/0) | bar     <- gates ph3 kh1 reads
//  ph3: read kh1 | stage B(t+2,0) | MFMA kh1 n01 | bar
//  ph4: stage A(t+2,1) | MFMA kh1 n23 | vmcnt(10/4/0) | bar     <- gates next ph1 kh0 reads
// Exact vmcnt ledger (2 insts/stage call):
//  ph2-end requires complete through B(t,1)@(t-1).ph1; issued after = A(t+1,0),B(t+1,0),
//    A(t+1,1),B(t+1,1),A(t+2,0) = 10 insts -> vmcnt(10); t==NT-2 -> 8; t==NT-1 -> 0.
//  ph4-end requires through B(t+1,0)@(t-1).ph3; after = A(t+1,1),B(t+1,1),A(t+2,0),
//    B(t+2,0),A(t+2,1) = 10 -> vmcnt(10); t==NT-2 -> 4; t==NT-1 -> 0.
//  Prologue stages 7 halves (14 insts); vmcnt(10) completes A(0,0),B(0,0).
// WAR safety: every fragment read is consumed by MFMAs in its own/following phase,
// hence drained before the phase-end barrier preceding the region's restage.
// RAW safety: every read set is preceded by (vmcnt gate + barrier); all waves run the
// same stage sequence, so per-wave vmcnt + barrier => collective completion.
// Swizzle: 16B k-chunk XOR (chunk ^ (row>>1)&3), pre-swizzled global source + swizzled
// ds_read (verified: 0 LDS bank conflicts in round-2 profile).
template<bool OUT_F32, bool HAS_BIAS>
__global__ __launch_bounds__(512, 2) void gemm256(
    const unsigned short* __restrict__ A1, int lda1, int K1,
    const unsigned short* __restrict__ A2, int lda2, int K2,
    const unsigned short* __restrict__ Bw, int ldb,
    void* __restrict__ Cout, int ldc,
    const float* __restrict__ bias)
{
  __shared__ __align__(128) char lds[131072];

  const int tid = threadIdx.x;
  const int l  = tid & 63;
  const int wv = tid >> 6;
  const int wr = wv >> 2, wc = wv & 3;     // 2 x 4 wave grid

  // XCD-aware bijective swizzle (nwg % 8 == 0 for our grids)
  const int nN = gridDim.x;
  int lin = blockIdx.y * nN + blockIdx.x;
  int nwg = nN * gridDim.y;
  int id2 = ((nwg & 7) == 0) ? ((lin & 7) * (nwg >> 3) + (lin >> 3)) : lin;
  const int bM = (id2 / nN) * 256;
  const int bN = (id2 % nN) * 256;

  const int NT1 = K1 >> 6;
  const int NT  = (K1 + K2) >> 6;

  // ---- staging: thread stages 16B chunks p=tid (row tid>>2) and p=tid+512
  // (row tid>>2 + 128); phys chunk tid&3; global col pre-swizzled.
  const int sr0  = tid >> 2;
  const int colE = ((tid & 3) ^ ((sr0 >> 1) & 3)) * 8;
  const unsigned short* pA1g0 = A1 + (size_t)(bM + sr0) * lda1 + colE;
  const unsigned short* pA1g1 = A1 + (size_t)(bM + sr0 + 128) * lda1 + colE;
  const unsigned short* pA2g0 = (K2 > 0) ? A2 + (size_t)(bM + sr0) * lda2 + colE : pA1g0;
  const unsigned short* pA2g1 = (K2 > 0) ? A2 + (size_t)(bM + sr0 + 128) * lda2 + colE : pA1g1;
  const unsigned short* pBg0  = Bw + (size_t)(bN + sr0) * ldb + colE;
  const unsigned short* pBg1  = Bw + (size_t)(bN + sr0 + 128) * ldb + colE;
  char* ldsw = lds + tid * 16;

  auto stageA = [&](int tt, int kh) {
    const unsigned short *p0, *p1; int tc;
    if (tt < NT1) { p0 = pA1g0; p1 = pA1g1; tc = (tt << 6) + (kh << 5); }
    else          { p0 = pA2g0; p1 = pA2g1; tc = ((tt - NT1) << 6) + (kh << 5); }
    unsigned off = (unsigned)((tt & 1) << 16) + (unsigned)(kh << 14);
    GLDS16(p0 + tc, ldsw + off);
    GLDS16(p1 + tc, ldsw + off + 8192);
  };
  auto stageB = [&](int tt, int kh) {
    int tc = (tt << 6) + (kh << 5);
    unsigned off = (unsigned)((tt & 1) << 16) + 32768u + (unsigned)(kh << 14);
    GLDS16(pBg0 + tc, ldsw + off);
    GLDS16(pBg1 + tc, ldsw + off + 8192);
  };

  // ---- fragment-read bases (swizzle invariant across 16-row strides)
  const int swz = ((l >> 4) ^ (((l & 15) >> 1) & 3)) << 4;
  const char* rdA0 = lds + ((wr * 128 + (l & 15)) * 64 + swz);
  const char* rdB0 = lds + (32768 + (wc * 64 + (l & 15)) * 64 + swz);

  f32x4 acc[8][4] = {};

  // ---- prologue: stage A0(0),B0(0),A0(1),B0(1),A(1,0),B(1,0),A(1,1)
  stageA(0, 0); stageB(0, 0); stageA(0, 1); stageB(0, 1);
  stageA(1, 0); stageB(1, 0); stageA(1, 1);
  asm volatile("s_waitcnt vmcnt(10)" ::: "memory");
  __builtin_amdgcn_s_barrier();

  for (int t = 0; t < NT; ++t) {
    const char* rA = rdA0 + ((t & 1) << 16);
    const char* rB = rdB0 + ((t & 1) << 16);
    bf16x8 af[8], bfr[4];

    // -------- ph1: kh0 reads | stage B(t+1,1) | MFMA n01 --------
    bfr[0] = *(const bf16x8*)(rB);
    bfr[1] = *(const bf16x8*)(rB + 1024);
#pragma unroll
    for (int m = 0; m < 8; ++m) af[m] = *(const bf16x8*)(rA + m * 1024);
    bfr[2] = *(const bf16x8*)(rB + 2048);
    bfr[3] = *(const bf16x8*)(rB + 3072);
    if (t + 1 < NT) stageB(t + 1, 1);
    __builtin_amdgcn_s_setprio(1);
#pragma unroll
    for (int m = 0; m < 8; ++m) {
      acc[m][0] = MFMA16(af[m], bfr[0], acc[m][0]);
      acc[m][1] = MFMA16(af[m], bfr[1], acc[m][1]);
    }
    __builtin_amdgcn_s_setprio(0);
    __builtin_amdgcn_s_barrier();

    // -------- ph2: stage A(t+2,0) | MFMA n23 | gate --------
    if (t + 2 < NT) stageA(t + 2, 0);
    __builtin_amdgcn_s_setprio(1);
#pragma unroll
    for (int m = 0; m < 8; ++m) {
      acc[m][2] = MFMA16(af[m], bfr[2], acc[m][2]);
      acc[m][3] = MFMA16(af[m], bfr[3], acc[m][3]);
    }
    __builtin_amdgcn_s_setprio(0);
    if (t < NT - 2)       asm volatile("s_waitcnt vmcnt(10)" ::: "memory");
    else if (t == NT - 2) asm volatile("s_waitcnt vmcnt(8)" ::: "memory");
    else                  asm volatile("s_waitcnt vmcnt(0)" ::: "memory");
    __builtin_amdgcn_s_barrier();

    // -------- ph3: kh1 reads | stage B(t+2,0) | MFMA n01 --------
    bfr[0] = *(const bf16x8*)(rB + 16384);
    bfr[1] = *(const bf16x8*)(rB + 16384 + 1024);
#pragma unroll
    for (int m = 0; m < 8; ++m) af[m] = *(const bf16x8*)(rA + 16384 + m * 1024);
    bfr[2] = *(const bf16x8*)(rB + 16384 + 2048);
    bfr[3] = *(const bf16x8*)(rB + 16384 + 3072);
    if (t + 2 < NT) stageB(t + 2, 0);
    __builtin_amdgcn_s_setprio(1);
#pragma unroll
    for (int m = 0; m < 8; ++m) {
      acc[m][0] = MFMA16(af[m], bfr[0], acc[m][0]);
      acc[m][1] = MFMA16(af[m], bfr[1], acc[m][1]);
    }
    __builtin_amdgcn_s_setprio(0);
    __builtin_amdgcn_s_barrier();

    // -------- ph4: stage A(t+2,1) | MFMA n23 | gate --------
    if (t + 2 < NT) stageA(t + 2, 1);
    __builtin_amdgcn_s_setprio(1);
#pragma unroll
    for (int m = 0; m < 8; ++m) {
      acc[m][2] = MFMA16(af[m], bfr[2], acc[m][2]);
      acc[m][3] = MFMA16(af[m], bfr[3], acc[m][3]);
    }
    __builtin_amdgcn_s_setprio(0);
    if (t < NT - 2)       asm volatile("s_waitcnt vmcnt(10)" ::: "memory");
    else if (t == NT - 2) asm volatile("s_waitcnt vmcnt(4)" ::: "memory");
    else                  asm volatile("s_waitcnt vmcnt(0)" ::: "memory");
    __builtin_amdgcn_s_barrier();
  }

  // ---- epilogue: C via LDS, coalesced 16B stores ----
  // MFMA D layout: row=(l>>4)*4+r, col=l&15 (verified m89/m91).
  // LDS tile swizzled on 16B chunks by ((row>>2)&3) to spread the 4-rows-per-wave
  // write pattern across banks; readout applies the same XOR.
  const int lr0 = wr * 128 + ((l >> 4) << 2);
  const int lc0 = wc * 64 + (l & 15);
  float bvals[4];
  if (HAS_BIAS) {
#pragma unroll
    for (int n = 0; n < 4; ++n) bvals[n] = bias[bN + lc0 + n * 16];
  }

  if (!OUT_F32) {
    unsigned short* lt = (unsigned short*)lds;    // [256][256] ushort
    unsigned short* Cp = (unsigned short*)Cout;
#pragma unroll
    for (int m = 0; m < 8; ++m)
#pragma unroll
      for (int n = 0; n < 4; ++n)
#pragma unroll
        for (int r = 0; r < 4; ++r) {
          float v = acc[m][n][r];
          if (HAS_BIAS) v += bvals[n];
          int row = lr0 + m * 16 + r;
          int col = lc0 + n * 16;
          int a = row * 256 + ((((col >> 3) ^ ((row >> 2) & 3)) << 3) | (col & 7));
          lt[a] = f2bf(v);
        }
    __syncthreads();
#pragma unroll
    for (int i = 0; i < 16; ++i) {
      int ch = i * 512 + tid;
      int row = ch >> 5, c = ch & 31;
      uint4 v = *(const uint4*)(lt + row * 256 + ((c ^ ((row >> 2) & 3)) << 3));
      *(uint4*)(Cp + (size_t)(bM + row) * ldc + bN + c * 8) = v;
    }
  } else {
    float* lf = (float*)lds;                      // [128][256] f32 per half
    float* Cp = (float*)Cout;
#pragma unroll
    for (int h = 0; h < 2; ++h) {
      if (wr == h) {
        const int lrh = (l >> 4) << 2;
#pragma unroll
        for (int m = 0; m < 8; ++m)
#pragma unroll
          for (int n = 0; n < 4; ++n)
#pragma unroll
            for (int r = 0; r < 4; ++r) {
              float v = acc[m][n][r];
              if (HAS_BIAS) v += bvals[n];
              int row = lrh + m * 16 + r;
              int col = lc0 + n * 16;
              int a = row * 256 + ((((col >> 2) ^ ((row >> 2) & 3)) << 2) | (col & 3));
              lf[a] = v;
            }
      }
      __syncthreads();
#pragma unroll
      for (int i = 0; i < 16; ++i) {
        int ch = i * 512 + tid;
        int row = ch >> 6, c = ch & 63;
        float4 v = *(const float4*)(lf + row * 256 + ((c ^ ((row >> 2) & 3)) << 2));
        *(float4*)(Cp + (size_t)(bM + h * 128 + row) * ldc + bN + c * 4) = v;
      }
      __syncthreads();
    }
  }
}

// ---------- attention (3 keys, 4 heads) ----------
__global__ __launch_bounds__(256) void attn_kernel(
    unsigned short* __restrict__ Yp,
    const float* __restrict__ bq,  const float* __restrict__ bkc,
    const float* __restrict__ bvc)
{
  const int b = blockIdx.x;
  const int h = threadIdx.x >> 6;
  const int l = threadIdx.x & 63;
  const int e0 = h * 256 + l * 4;

  const float4 bqv = *(const float4*)(bq + e0);
  const float4 bkv = *(const float4*)(bkc + e0);
  const float4 bvv = *(const float4*)(bvc + e0);

  float q[4][4], kc[4][4], vc[4][4];
  size_t rb[4];
#pragma unroll
  for (int i = 0; i < 4; ++i) {
    rb[i] = ((size_t)i * 8192 + b) * 3072;
    ushort4 qq = *(const ushort4*)(Yp + rb[i] + 2048 + e0);
    ushort4 kk = *(const ushort4*)(Yp + rb[i] + e0);
    ushort4 vv = *(const ushort4*)(Yp + rb[i] + 1024 + e0);
    q[i][0] = bf2f(qq.x) + bqv.x; q[i][1] = bf2f(qq.y) + bqv.y;
    q[i][2] = bf2f(qq.z) + bqv.z; q[i][3] = bf2f(qq.w) + bqv.w;
    kc[i][0] = bf2f(kk.x); kc[i][1] = bf2f(kk.y);
    kc[i][2] = bf2f(kk.z); kc[i][3] = bf2f(kk.w);
    vc[i][0] = bf2f(vv.x); vc[i][1] = bf2f(vv.y);
    vc[i][2] = bf2f(vv.z); vc[i][3] = bf2f(vv.w);
  }

  float u[4][4], tb[4];
#pragma unroll
  for (int i = 0; i < 4; ++i) {
    tb[i] = q[i][0]*bkv.x + q[i][1]*bkv.y + q[i][2]*bkv.z + q[i][3]*bkv.w;
#pragma unroll
    for (int j = 0; j < 4; ++j)
      u[i][j] = q[i][0]*kc[j][0] + q[i][1]*kc[j][1] + q[i][2]*kc[j][2] + q[i][3]*kc[j][3];
  }
#pragma unroll
  for (int d = 1; d < 64; d <<= 1) {
#pragma unroll
    for (int i = 0; i < 4; ++i) {
      tb[i] += __shfl_xor(tb[i], d);
#pragma unroll
      for (int j = 0; j < 4; ++j) u[i][j] += __shfl_xor(u[i][j], d);
    }
  }

#pragma unroll
  for (int i = 0; i < 4; ++i) {
    float s[4], a[4];
    float mx = -1e30f;
#pragma unroll
    for (int j = 0; j < 4; ++j) {
      s[j] = (u[i][i] - u[i][j] + tb[i]) * 0.0625f;
      if (j != i) mx = fmaxf(mx, s[j]);
    }
    float den = 0.f;
#pragma unroll
    for (int j = 0; j < 4; ++j) {
      a[j] = (j == i) ? 0.f : __expf(s[j] - mx);
      den += a[j];
    }
    float inv = 1.f / den;
#pragma unroll
    for (int j = 0; j < 4; ++j) a[j] *= inv;

    float o0 = vc[i][0] + bvv.x, o1 = vc[i][1] + bvv.y;
    float o2 = vc[i][2] + bvv.z, o3 = vc[i][3] + bvv.w;
#pragma unroll
    for (int j = 0; j < 4; ++j) {
      o0 -= a[j] * vc[j][0]; o1 -= a[j] * vc[j][1];
      o2 -= a[j] * vc[j][2]; o3 -= a[j] * vc[j][3];
    }
    ushort4 w;
    w.x = f2bf(o0); w.y = f2bf(o1); w.z = f2bf(o2); w.w = f2bf(o3);
    *(ushort4*)(Yp + rb[i] + 2048 + e0) = w;
  }
}

// ---------- logits ----------
__global__ __launch_bounds__(256) void logits_kernel(
    const float* __restrict__ feats, const float* __restrict__ Wc,
    const float* __restrict__ bc, float* __restrict__ out)
{
  __shared__ float w[4096];
  const int t = threadIdx.x;
  for (int i = t; i < 4096; i += 256) w[i] = Wc[i];
  __syncthreads();
  const int wave = t >> 6, l = t & 63;
  const int row = blockIdx.x * 4 + wave;
  const float* f = feats + (size_t)row * 1024;
  float s0 = 0.f, s1 = 0.f, s2 = 0.f, s3 = 0.f;
#pragma unroll
  for (int c4 = 0; c4 < 4; ++c4) {
    int e = c4 * 256 + l * 4;
    float4 x  = *(const float4*)(f + e);
    float4 w0 = *(const float4*)(w + e);
    float4 w1 = *(const float4*)(w + 1024 + e);
    float4 w2 = *(const float4*)(w + 2048 + e);
    float4 w3 = *(const float4*)(w + 3072 + e);
    s0 += x.x*w0.x + x.y*w0.y + x.z*w0.z + x.w*w0.w;
    s1 += x.x*w1.x + x.y*w1.y + x.z*w1.z + x.w*w1.w;
    s2 += x.x*w2.x + x.y*w2.y + x.z*w2.z + x.w*w2.w;
    s3 += x.x*w3.x + x.y*w3.y + x.z*w3.z + x.w*w3.w;
  }
#pragma unroll
  for (int d = 1; d < 64; d <<= 1) {
    s0 += __shfl_xor(s0, d); s1 += __shfl_xor(s1, d);
    s2 += __shfl_xor(s2, d); s3 += __shfl_xor(s3, d);
  }
  if (l < 4) {
    float s = (l == 0) ? s0 : (l == 1) ? s1 : (l == 2) ? s2 : s3;
    out[(size_t)row * 4 + l] = s + bc[l];
  }
}

// ---------- launch ----------
extern "C" void kernel_launch(void* const* d_in, const int* in_sizes, int n_in,
                              void* d_out, int out_size, void* d_ws, size_t ws_size,
                              hipStream_t stream) {
  const float* X1   = (const float*)d_in[0];
  const float* X2   = (const float*)d_in[1];
  const float* X3   = (const float*)d_in[2];
  const float* X4   = (const float*)d_in[3];
  const float* Wq   = (const float*)d_in[4];
  const float* bq   = (const float*)d_in[5];
  // d_in[6] Wk_s, d_in[7] bk_s: unused (softmax over a single key == identity)
  const float* Wv_s = (const float*)d_in[8];
  const float* bv_s = (const float*)d_in[9];
  const float* Wo_s = (const float*)d_in[10];
  const float* bo_s = (const float*)d_in[11];
  const float* Wk_c = (const float*)d_in[12];
  const float* bk_c = (const float*)d_in[13];
  const float* Wv_c = (const float*)d_in[14];
  const float* bv_c = (const float*)d_in[15];
  const float* Wo_c = (const float*)d_in[16];
  const float* bo_c = (const float*)d_in[17];
  const float* Wc   = (const float*)d_in[18];
  const float* bc   = (const float*)d_in[19];

  char* ws = (char*)d_ws;
  unsigned short* Xcat   = (unsigned short*)(ws + 0);
  unsigned short* Wcat   = (unsigned short*)(ws + 67108864);
  unsigned short* WoM2   = (unsigned short*)(ws + 73400320);
  unsigned short* Wos_bf = (unsigned short*)(ws + 77594624);
  unsigned short* WvsT   = (unsigned short*)(ws + 79691776);
  float*          bias2  = (float*)        (ws + 81788928);
  unsigned short* Yproj  = (unsigned short*)(ws + 81793024);
  float* out = (float*)d_out;

  convert_x<<<32768, 256, 0, stream>>>(X1, X2, X3, X4, Xcat);
  prep_w<<<5120, 256, 0, stream>>>(Wq, Wk_c, Wv_c, Wo_c, Wo_s, Wcat, WoM2, Wos_bf);
  transpose_wvs<<<dim3(32, 32), 256, 0, stream>>>(Wv_s, WvsT);
  bias2_kernel<<<256, 256, 0, stream>>>(Wo_s, bv_s, bo_c, bo_s, bias2);
  // M2 = Wo_s @ Wv_s  -> WoM2 cols 1024..2047 (small, keep proven 128^2 kernel)
  gemm_bt<false, false><<<dim3(8, 8), 256, 0, stream>>>(
      Wos_bf, 1024, 1024, nullptr, 0, 0, WvsT, 1024,
      (void*)(WoM2 + 1024), 2048, nullptr);
  // Yproj[i*B+b, :] = [KcX | VcX | QX]   (256^2 4-phase)
  gemm256<false, false><<<dim3(12, 128), 512, 0, stream>>>(
      Xcat, 1024, 1024, nullptr, 0, 0, Wcat, 1024,
      (void*)Yproj, 3072, nullptr);
  attn_kernel<<<8192, 256, 0, stream>>>(Yproj, bq, bk_c, bv_c);
  // d = [A | X] @ [Wo_c | M2]^T + bias2   (256^2 4-phase, dual-A concat)
  gemm256<true, true><<<dim3(4, 128), 512, 0, stream>>>(
      Yproj + 2048, 3072, 1024, Xcat, 1024, 1024, WoM2, 2048,
      (void*)out, 1024, bias2);
  logits_kernel<<<8192, 256, 0, stream>>>(out, Wc, bc, out + 33554432);
}